// Round 1
// baseline (2376.747 us; speedup 1.0000x reference)
//
#include <hip/hip_runtime.h>

// PoseCDE: B=64, L=63, H=512, C=513, N_EVAL=10.
// Key reduction: all RK4 stage times t ∈ [0.1,1.0] -> ceil(t)-1 == 0 -> dXdt is
// always derivs[:,0] = (ts[:,2]-ts[:,1], 0,...,0). So the [H, H*C] Wout matmul
// reduces to the strided column slice W0col[k][h] = Wout[k][h*513].
// f(t,z) = dt0[b] * tanh(relu(relu(z@Wf0+bf0)@Wf1+bf1) @ W0col + b0col).

#define Hdim 512
#define Bsz  64
#define HC   262656  // H*C

// workspace float offsets
#define OFF_W0COL 0        // 512*512
#define OFF_B0COL 262144   // 512
#define OFF_DT0   262656   // 64
#define OFF_Z     262720   // 64*512
#define OFF_K     295488   // 4 * 64*512
#define OFF_H1    426560   // 64*512
#define OFF_H2    459328   // 64*512
#define OFF_HI    492096   // 64*10*512  -> total 819776 floats (~3.3 MB)

__global__ void prep_kernel(const float* __restrict__ Wout,
                            const float* __restrict__ bout,
                            const float* __restrict__ ts,
                            float* __restrict__ ws) {
  int i = blockIdx.x * blockDim.x + threadIdx.x;
  if (i < 262144) {
    int k = i >> 9, h = i & 511;
    ws[OFF_W0COL + i] = Wout[(size_t)k * HC + (size_t)h * 513];
  } else if (i < 262144 + 512) {
    int h = i - 262144;
    ws[OFF_B0COL + h] = bout[(size_t)h * 513];
  } else if (i < 262144 + 512 + 64) {
    int b = i - (262144 + 512);
    ws[OFF_DT0 + b] = ts[b * 64 + 2] - ts[b * 64 + 1];
  } else if (i < 262144 + 512 + 64 + 32768) {
    int j = i - (262144 + 512 + 64);
    ws[OFF_Z + j] = 0.f;
  } else if (i < 262144 + 512 + 64 + 32768 + 32768) {
    int j = i - (262144 + 512 + 64 + 32768);
    int b = j >> 9, h = j & 511;
    ws[OFF_HI + b * 5120 + h] = 0.f;  // h_i[:,0] = z0 = 0
  }
}

// out = relu((Az + c*Ak) @ W + bias); [64,512] @ [512,512]
// grid 128 WGs x 256 threads: WG = 8 batches x 32 cols, 1 thread/output.
__global__ __launch_bounds__(256) void gemm_relu_kernel(
    const float* __restrict__ Az, const float* __restrict__ Ak, float c,
    const float* __restrict__ W, const float* __restrict__ bias,
    float* __restrict__ out) {
  int wg_b = blockIdx.x >> 4;   // 0..7
  int wg_c = blockIdx.x & 15;   // 0..15
  int n = wg_c * 32 + (threadIdx.x & 31);
  int b = wg_b * 8 + (threadIdx.x >> 5);
  const float* arow = Az + b * Hdim;
  const float* krow = Ak + b * Hdim;
  const float* wp = W + n;
  float a0 = 0.f, a1 = 0.f, a2 = 0.f, a3 = 0.f;
  if (c != 0.f) {
    for (int k = 0; k < Hdim; k += 4) {
      float4 av = *(const float4*)(arow + k);
      float4 kv = *(const float4*)(krow + k);
      a0 += (av.x + c * kv.x) * wp[(k + 0) * Hdim];
      a1 += (av.y + c * kv.y) * wp[(k + 1) * Hdim];
      a2 += (av.z + c * kv.z) * wp[(k + 2) * Hdim];
      a3 += (av.w + c * kv.w) * wp[(k + 3) * Hdim];
    }
  } else {
    for (int k = 0; k < Hdim; k += 4) {
      float4 av = *(const float4*)(arow + k);
      a0 += av.x * wp[(k + 0) * Hdim];
      a1 += av.y * wp[(k + 1) * Hdim];
      a2 += av.z * wp[(k + 2) * Hdim];
      a3 += av.w * wp[(k + 3) * Hdim];
    }
  }
  float acc = bias[n] + ((a0 + a1) + (a2 + a3));
  out[b * Hdim + n] = fmaxf(acc, 0.f);
}

// kout = dt0[b] * tanh(A @ W0col + b0col); optionally final RK4 z-update.
__global__ __launch_bounds__(256) void gemm_tanh_kernel(
    const float* __restrict__ A, const float* __restrict__ W,
    const float* __restrict__ bias, const float* __restrict__ dt0,
    float* __restrict__ kout,
    const float* __restrict__ k1, const float* __restrict__ k2,
    const float* __restrict__ k3,
    float* __restrict__ z, float* __restrict__ hi_row, int do_update) {
  int wg_b = blockIdx.x >> 4;
  int wg_c = blockIdx.x & 15;
  int n = wg_c * 32 + (threadIdx.x & 31);
  int b = wg_b * 8 + (threadIdx.x >> 5);
  const float* arow = A + b * Hdim;
  const float* wp = W + n;
  float a0 = 0.f, a1 = 0.f, a2 = 0.f, a3 = 0.f;
  for (int k = 0; k < Hdim; k += 4) {
    float4 av = *(const float4*)(arow + k);
    a0 += av.x * wp[(k + 0) * Hdim];
    a1 += av.y * wp[(k + 1) * Hdim];
    a2 += av.z * wp[(k + 2) * Hdim];
    a3 += av.w * wp[(k + 3) * Hdim];
  }
  float acc = bias[n] + ((a0 + a1) + (a2 + a3));
  float kv = dt0[b] * tanhf(acc);
  int idx = b * Hdim + n;
  kout[idx] = kv;
  if (do_update) {
    float zn = z[idx] + (0.1f / 6.f) *
               (k1[idx] + 2.f * k2[idx] + 2.f * k3[idx] + kv);
    z[idx] = zn;
    hi_row[b * 5120 + n] = zn;
  }
}

// poses[b,s,:] = leaky_relu(h_i[b,s]@Wr1+br1, 0.1) @ Wr2 + br2
__global__ __launch_bounds__(128) void regressor_kernel(
    const float* __restrict__ ws, const float* __restrict__ Wr1,
    const float* __restrict__ br1, const float* __restrict__ Wr2,
    const float* __restrict__ br2, float* __restrict__ out) {
  int b = blockIdx.x / 10, s = blockIdx.x % 10;
  const float* hrow = ws + OFF_HI + b * 5120 + s * 512;
  int j = threadIdx.x;
  float acc = br1[j];
  for (int k = 0; k < Hdim; ++k) acc += hrow[k] * Wr1[k * 128 + j];
  float hr = acc > 0.f ? acc : 0.1f * acc;
  __shared__ float sh[128];
  sh[j] = hr;
  __syncthreads();
  if (j < 6) {
    float p = br2[j];
    for (int k = 0; k < 128; ++k) p += sh[k] * Wr2[k * 6 + j];
    out[b * 60 + s * 6 + j] = p;
  }
}

__global__ void copy_final_kernel(const float* __restrict__ ws,
                                  float* __restrict__ out) {
  int i = blockIdx.x * blockDim.x + threadIdx.x;
  if (i < 32768) {
    int b = i >> 9, h = i & 511;
    out[3840 + i] = ws[OFF_HI + b * 5120 + 9 * 512 + h];
  }
}

extern "C" void kernel_launch(void* const* d_in, const int* in_sizes, int n_in,
                              void* d_out, int out_size, void* d_ws, size_t ws_size,
                              hipStream_t stream) {
  const float* ts   = (const float*)d_in[2];
  const float* Wf0  = (const float*)d_in[3];
  const float* bf0  = (const float*)d_in[4];
  const float* Wf1  = (const float*)d_in[5];
  const float* bf1  = (const float*)d_in[6];
  const float* Wout = (const float*)d_in[7];
  const float* bout = (const float*)d_in[8];
  const float* Wr1  = (const float*)d_in[9];
  const float* br1  = (const float*)d_in[10];
  const float* Wr2  = (const float*)d_in[11];
  const float* br2  = (const float*)d_in[12];
  float* out = (float*)d_out;
  float* ws  = (float*)d_ws;

  float* W0col = ws + OFF_W0COL;
  float* b0col = ws + OFF_B0COL;
  float* dt0   = ws + OFF_DT0;
  float* z     = ws + OFF_Z;
  float* kbuf  = ws + OFF_K;
  float* h1    = ws + OFF_H1;
  float* h2    = ws + OFF_H2;
  float* hi    = ws + OFF_HI;

  prep_kernel<<<(328256 + 255) / 256, 256, 0, stream>>>(Wout, bout, ts, ws);

  const float hstep = 0.1f;
  const float cs[4] = {0.f, 0.5f * hstep, 0.5f * hstep, hstep};
  for (int step = 0; step < 9; ++step) {
    for (int s = 0; s < 4; ++s) {
      const float* kprev = (s == 0) ? z : (kbuf + (s - 1) * 32768);
      gemm_relu_kernel<<<128, 256, 0, stream>>>(z, kprev, cs[s], Wf0, bf0, h1);
      gemm_relu_kernel<<<128, 256, 0, stream>>>(h1, h1, 0.f, Wf1, bf1, h2);
      gemm_tanh_kernel<<<128, 256, 0, stream>>>(
          h2, W0col, b0col, dt0, kbuf + s * 32768,
          kbuf, kbuf + 32768, kbuf + 2 * 32768,
          z, hi + (step + 1) * 512, (s == 3) ? 1 : 0);
    }
  }
  regressor_kernel<<<640, 128, 0, stream>>>(ws, Wr1, br1, Wr2, br2, out);
  copy_final_kernel<<<(32768 + 255) / 256, 256, 0, stream>>>(ws, out);
}

// Round 2
// 1560.063 us; speedup vs baseline: 1.5235x; 1.5235x over previous
//
#include <hip/hip_runtime.h>
#include <math.h>

// PoseCDE: B=64, L=63, H=512, C=513, N_EVAL=10.
// Reduction: all RK4 stage times t in [0.1,1.0] -> ceil(t)-1 == 0 -> dXdt is
// always derivs[:,0] = (ts[:,2]-ts[:,1], 0,...,0). So the [H,H*C] Wout matmul
// reduces to column slice W0col[k][h] = Wout[k][h*513], and
// f(z) = dt0[b] * tanh(relu(relu(z@Wf0+bf0)@Wf1+bf1) @ W0col + b0col).
//
// Structure: batches are independent -> ONE persistent workgroup per 2 batches
// runs the whole 9-step RK4 (108 sequential 512x512 layers) + regressor with
// only __syncthreads() (no kernel-launch boundaries, no grid syncs).
// 32 WGs x 512 threads; thread = (col-quad c in [0,128), k-quarter q in [0,4)),
// handles both batches: dwordx4 W loads (coalesced, each W element read once
// per WG), LDS-broadcast inputs, 8 FMA per quad, split-K reduce through LDS.

#define OFF_W0COL 0        // 512*512 floats
#define OFF_B0COL 262144   // 512
#define OFF_DT0   262656   // 64
#define OFF_HI    262720   // 64*10*512 floats (h_i for regressor)

__global__ void prep_kernel(const float* __restrict__ Wout,
                            const float* __restrict__ bout,
                            const float* __restrict__ ts,
                            float* __restrict__ ws) {
  int i = blockIdx.x * blockDim.x + threadIdx.x;
  if (i < 262144) {
    int k = i >> 9, h = i & 511;
    ws[OFF_W0COL + i] = Wout[(size_t)k * 262656 + (size_t)h * 513];
  } else if (i < 262144 + 512) {
    int h = i - 262144;
    ws[OFF_B0COL + h] = bout[(size_t)h * 513];
  } else if (i < 262144 + 512 + 64) {
    int b = i - (262144 + 512);
    ws[OFF_DT0 + b] = ts[b * 64 + 2] - ts[b * 64 + 1];
  }
}

// Partial-sum phase of one [2,512]@[512,512] layer.
// Thread (c,q): cols 4c..4c+3, k in [128q,128q+128), both batches.
// part layout: part[(2q+b)*512 + n].
__device__ __forceinline__ void layer_partials(
    const float* __restrict__ W, const float* in0, const float* in1,
    float* part, int c, int q) {
  float a00 = 0.f, a01 = 0.f, a02 = 0.f, a03 = 0.f;
  float a10 = 0.f, a11 = 0.f, a12 = 0.f, a13 = 0.f;
  const float* wp = W + (size_t)(q * 128) * 512 + c * 4;
  const float* p0 = in0 + q * 128;
  const float* p1 = in1 + q * 128;
#pragma unroll 2
  for (int kk = 0; kk < 128; kk += 4) {
    float4 i0 = *(const float4*)(p0 + kk);
    float4 i1 = *(const float4*)(p1 + kk);
    float4 w0 = *(const float4*)(wp);
    float4 w1 = *(const float4*)(wp + 512);
    float4 w2 = *(const float4*)(wp + 1024);
    float4 w3 = *(const float4*)(wp + 1536);
    wp += 2048;
    a00 = fmaf(i0.x, w0.x, a00); a01 = fmaf(i0.x, w0.y, a01);
    a02 = fmaf(i0.x, w0.z, a02); a03 = fmaf(i0.x, w0.w, a03);
    a10 = fmaf(i1.x, w0.x, a10); a11 = fmaf(i1.x, w0.y, a11);
    a12 = fmaf(i1.x, w0.z, a12); a13 = fmaf(i1.x, w0.w, a13);
    a00 = fmaf(i0.y, w1.x, a00); a01 = fmaf(i0.y, w1.y, a01);
    a02 = fmaf(i0.y, w1.z, a02); a03 = fmaf(i0.y, w1.w, a03);
    a10 = fmaf(i1.y, w1.x, a10); a11 = fmaf(i1.y, w1.y, a11);
    a12 = fmaf(i1.y, w1.z, a12); a13 = fmaf(i1.y, w1.w, a13);
    a00 = fmaf(i0.z, w2.x, a00); a01 = fmaf(i0.z, w2.y, a01);
    a02 = fmaf(i0.z, w2.z, a02); a03 = fmaf(i0.z, w2.w, a03);
    a10 = fmaf(i1.z, w2.x, a10); a11 = fmaf(i1.z, w2.y, a11);
    a12 = fmaf(i1.z, w2.z, a12); a13 = fmaf(i1.z, w2.w, a13);
    a00 = fmaf(i0.w, w3.x, a00); a01 = fmaf(i0.w, w3.y, a01);
    a02 = fmaf(i0.w, w3.z, a02); a03 = fmaf(i0.w, w3.w, a03);
    a10 = fmaf(i1.w, w3.x, a10); a11 = fmaf(i1.w, w3.y, a11);
    a12 = fmaf(i1.w, w3.z, a12); a13 = fmaf(i1.w, w3.w, a13);
  }
  *(float4*)(part + (q * 2 + 0) * 512 + c * 4) = make_float4(a00, a01, a02, a03);
  *(float4*)(part + (q * 2 + 1) * 512 + c * 4) = make_float4(a10, a11, a12, a13);
}

__global__ __launch_bounds__(512, 1) void cde_main(
    const float* __restrict__ Wf0, const float* __restrict__ bf0,
    const float* __restrict__ Wf1, const float* __restrict__ bf1,
    float* __restrict__ ws,
    const float* __restrict__ Wr1, const float* __restrict__ br1,
    const float* __restrict__ Wr2, const float* __restrict__ br2,
    float* __restrict__ out) {
  __shared__ float bufA[2 * 512];
  __shared__ float bufB[2 * 512];
  __shared__ float zb[2 * 512];
  __shared__ float kb[2 * 512];
  __shared__ float accb[2 * 512];
  __shared__ float part[8 * 512];
  __shared__ float hrbuf[20][128];   // total LDS = 46 KB

  const int t = threadIdx.x;
  const int c = t & 127, q = t >> 7;
  const int wg = blockIdx.x;
  const float* W0col = ws + OFF_W0COL;
  const float* b0col = ws + OFF_B0COL;
  float* hi = ws + OFF_HI;           // [64][10][512]
  const float dt0v[2] = { ws[OFF_DT0 + 2 * wg], ws[OFF_DT0 + 2 * wg + 1] };

  // init: z = 0, k = 0, h_i[:,0] = 0
  for (int o = t; o < 1024; o += 512) {
    zb[o] = 0.f;
    kb[o] = 0.f;
    int b = o >> 9, n = o & 511;
    hi[(2 * wg + b) * 5120 + n] = 0.f;
  }
  __syncthreads();

  const float hs = 0.1f;
  for (int step = 0; step < 9; ++step) {
    for (int s = 0; s < 4; ++s) {
      const float cs = (s == 0) ? 0.f : ((s == 3) ? hs : 0.5f * hs);
      // stage input: bufA = z + cs * k_prev
      for (int o = t; o < 1024; o += 512)
        bufA[o] = zb[o] + cs * kb[o];
      __syncthreads();
      // layer 1: bufB = relu(bufA @ Wf0 + bf0)
      layer_partials(Wf0, bufA, bufA + 512, part, c, q);
      __syncthreads();
      for (int o = t; o < 1024; o += 512) {
        int b = o >> 9, n = o & 511;
        float v = bf0[n] + ((part[b * 512 + n] + part[(2 + b) * 512 + n]) +
                            (part[(4 + b) * 512 + n] + part[(6 + b) * 512 + n]));
        bufB[o] = fmaxf(v, 0.f);
      }
      __syncthreads();
      // layer 2: bufA = relu(bufB @ Wf1 + bf1)
      layer_partials(Wf1, bufB, bufB + 512, part, c, q);
      __syncthreads();
      for (int o = t; o < 1024; o += 512) {
        int b = o >> 9, n = o & 511;
        float v = bf1[n] + ((part[b * 512 + n] + part[(2 + b) * 512 + n]) +
                            (part[(4 + b) * 512 + n] + part[(6 + b) * 512 + n]));
        bufA[o] = fmaxf(v, 0.f);
      }
      __syncthreads();
      // layer 3: k = dt0 * tanh(bufA @ W0col + b0col); RK4 accumulate
      layer_partials(W0col, bufA, bufA + 512, part, c, q);
      __syncthreads();
      for (int o = t; o < 1024; o += 512) {
        int b = o >> 9, n = o & 511;
        float v = b0col[n] + ((part[b * 512 + n] + part[(2 + b) * 512 + n]) +
                              (part[(4 + b) * 512 + n] + part[(6 + b) * 512 + n]));
        float kv = dt0v[b] * tanhf(v);
        if (s == 0) {
          accb[o] = kv;
        } else if (s == 3) {
          float zn = zb[o] + (hs / 6.f) * (accb[o] + kv);
          zb[o] = zn;
          hi[(2 * wg + b) * 5120 + (step + 1) * 512 + n] = zn;
        } else {
          accb[o] = accb[o] + 2.f * kv;
        }
        kb[o] = kv;
      }
      __syncthreads();
    }
  }

  // regressor: hr = leaky_relu(h_i @ Wr1 + br1, 0.1); poses = hr @ Wr2 + br2
  {
    int j = t & 127;
    for (int r = t >> 7; r < 20; r += 4) {   // r = bl*10 + s2
      int bl = r / 10, s2 = r - bl * 10;
      const float* h = hi + (2 * wg + bl) * 5120 + s2 * 512;
      float acc = br1[j];
#pragma unroll 4
      for (int k = 0; k < 512; ++k)
        acc = fmaf(h[k], Wr1[k * 128 + j], acc);
      hrbuf[r][j] = acc > 0.f ? acc : 0.1f * acc;
    }
  }
  __syncthreads();
  if (t < 120) {
    int r = t / 6, j = t - r * 6;
    int bl = r / 10, s2 = r - bl * 10;
    float p = br2[j];
#pragma unroll
    for (int k = 0; k < 128; ++k)
      p = fmaf(hrbuf[r][k], Wr2[k * 6 + j], p);
    out[(2 * wg + bl) * 60 + s2 * 6 + j] = p;
  }
  // final hidden state: out[3840 + b*512 + n] = z_final
  for (int o = t; o < 1024; o += 512) {
    int b = o >> 9, n = o & 511;
    out[3840 + (2 * wg + b) * 512 + n] = zb[o];
  }
}

extern "C" void kernel_launch(void* const* d_in, const int* in_sizes, int n_in,
                              void* d_out, int out_size, void* d_ws, size_t ws_size,
                              hipStream_t stream) {
  const float* ts   = (const float*)d_in[2];
  const float* Wf0  = (const float*)d_in[3];
  const float* bf0  = (const float*)d_in[4];
  const float* Wf1  = (const float*)d_in[5];
  const float* bf1  = (const float*)d_in[6];
  const float* Wout = (const float*)d_in[7];
  const float* bout = (const float*)d_in[8];
  const float* Wr1  = (const float*)d_in[9];
  const float* br1  = (const float*)d_in[10];
  const float* Wr2  = (const float*)d_in[11];
  const float* br2  = (const float*)d_in[12];
  float* out = (float*)d_out;
  float* ws  = (float*)d_ws;

  prep_kernel<<<(262720 + 255) / 256, 256, 0, stream>>>(Wout, bout, ts, ws);
  cde_main<<<32, 512, 0, stream>>>(Wf0, bf0, Wf1, bf1, ws,
                                   Wr1, br1, Wr2, br2, out);
}